// Round 5
// baseline (5322.451 us; speedup 1.0000x reference)
//
#include <hip/hip_runtime.h>
#include <math.h>

#define HID 256
#define TWOH 512
#define ROWS 8192   // B*S
#define NLAYER 4
#define TMAX 50
#define DT 0.05f
#define EPSC 1e-3f

typedef __bf16 bf16;
typedef __bf16 bf16x8 __attribute__((ext_vector_type(8)));
typedef float f32x4 __attribute__((ext_vector_type(4)));

// ---------------------------------------------------------------------------
// Fragment-major weight packing. Logical B[n][k] per layer with interleaved
// columns: n=2d -> tau col d (Wt[d][k]); n=2d+1 -> forcing col d
// (k<256 ? Wi[d][k] : Ws[d][k-256]).
// Wave wv, k-chunk ci, n-tile nt reads ONE contiguous 1-KB fragment:
// e = (((L*8+wv)*16+ci)*4+nt)*512 + lane*8 + j,
// n = wv*64 + nt*16 + (lane&15), k = ci*32 + (lane>>4)*8 + j.
// ---------------------------------------------------------------------------
__global__ void pack_w_kernel(const float* __restrict__ Ws,
                              const float* __restrict__ Wi,
                              const float* __restrict__ Wt,
                              bf16* __restrict__ Wf) {
    int e = blockIdx.x * 256 + threadIdx.x;     // [0, 4*512*512)
    int j    = e & 7;
    int lane = (e >> 3) & 63;
    int nt   = (e >> 9) & 3;
    int ci   = (e >> 11) & 15;
    int wv   = (e >> 15) & 7;
    int L    = (e >> 18);
    int n = wv * 64 + nt * 16 + (lane & 15);
    int k = ci * 32 + (lane >> 4) * 8 + j;
    int d = n >> 1;
    float v;
    if ((n & 1) == 0) {
        v = Wt[(size_t)L * HID * TWOH + (size_t)d * TWOH + k];
    } else {
        v = (k < HID) ? Wi[(size_t)L * HID * HID + (size_t)d * HID + k]
                      : Ws[(size_t)L * HID * HID + (size_t)d * HID + (k - HID)];
    }
    Wf[e] = (bf16)v;
}

__global__ void pack_b_kernel(const float* __restrict__ bs,
                              const float* __restrict__ bi,
                              const float* __restrict__ bt,
                              float* __restrict__ bp) {
    int idx = blockIdx.x * 256 + threadIdx.x;   // [0, 4*512)
    int L = idx / TWOH;
    int n = idx % TWOH;
    int d = n >> 1;
    bp[idx] = ((n & 1) == 0) ? bt[L * HID + d]
                             : (bs[L * HID + d] + bi[L * HID + d]);
}

// ---------------------------------------------------------------------------
// Persistent kernel: block b owns rows [32b, 32b+32) for all 50 t x 4 layers.
// States LDS-resident bf16 (XOR-swizzled). Weights stream L2 -> registers as
// contiguous 1-KB fragments, depth-3 prefetch. 8 waves split n (64 each).
// Layer loop fully unrolled: all per-layer state statically indexed (no
// alloca promotion / spill). (512,2): min 2 waves/EU -> 256-VGPR budget.
// ---------------------------------------------------------------------------
__global__ __launch_bounds__(512, 2) void persistent_kernel(
    const float* __restrict__ x,
    const bf16* __restrict__ Wf,
    const float* __restrict__ bp,
    float* __restrict__ deltas,
    float* __restrict__ out)
{
    __shared__ bf16 sX[32 * 256];            // 16 KB
    __shared__ bf16 sH[NLAYER][32 * 256];    // 64 KB
    __shared__ float sRed[8];

    const int tid  = threadIdx.x;
    const int lane = tid & 63;
    const int wv   = tid >> 6;               // 0..7
    const int l15  = lane & 15;
    const int quad = lane >> 4;              // 0..3
    const int w64  = wv * 64;
    const size_t rowbase = (size_t)blockIdx.x * 32;

    // ---- stage x -> sX (bf16, swizzled); zero sH ----
    #pragma unroll
    for (int it = 0; it < 2; ++it) {
        int s = tid + it * 512;              // 32 rows x 32 segs
        int r = s >> 5, seg = s & 31;
        const float* gx = x + (rowbase + r) * HID + seg * 8;
        float4 v0 = *(const float4*)gx;
        float4 v1 = *(const float4*)(gx + 4);
        bf16x8 o;
        o[0]=(bf16)v0.x; o[1]=(bf16)v0.y; o[2]=(bf16)v0.z; o[3]=(bf16)v0.w;
        o[4]=(bf16)v1.x; o[5]=(bf16)v1.y; o[6]=(bf16)v1.z; o[7]=(bf16)v1.w;
        int pseg = (seg & 24) | ((seg & 7) ^ (r & 7));
        *(bf16x8*)&sX[r * 256 + pseg * 8] = o;
    }
    {
        bf16x8 z = {};
        bf16* hflat = &sH[0][0];
        #pragma unroll
        for (int it = 0; it < 8; ++it)
            *(bf16x8*)&hflat[(size_t)(tid + it * 512) * 8] = z;
    }

    // ---- hoist biases (statically indexed after full unroll) ----
    float2 bias[NLAYER][4];
    #pragma unroll
    for (int L = 0; L < NLAYER; ++L)
        #pragma unroll
        for (int nt = 0; nt < 4; ++nt)
            bias[L][nt] = *(const float2*)(bp + L * TWOH + 2 * ((w64 + nt * 16 + l15) >> 1));

    __syncthreads();

    for (int t = 0; t < TMAX; ++t) {
        float dmax = 0.0f;
        #pragma unroll
        for (int L = 0; L < NLAYER; ++L) {
            const bf16* Alo = (L == 0) ? sX : sH[L - 1];   // k < 256 (cur_in)
            bf16*       Ahi = sH[L];                       // k >= 256 (h_prev)
            // wave's fragment stream: 64 KB contiguous per (L, wv)
            const bf16* wb = Wf + ((size_t)(L * 8 + wv) * 32768) + (size_t)lane * 8;

            f32x4 acc[2][4];
            #pragma unroll
            for (int mt = 0; mt < 2; ++mt)
                #pragma unroll
                for (int nt = 0; nt < 4; ++nt)
                    acc[mt][nt] = (f32x4){0.f, 0.f, 0.f, 0.f};

            // depth-3 register prefetch of B fragments (1 KB each, contiguous)
            bf16x8 bb[3][4];
            #pragma unroll
            for (int pi = 0; pi < 3; ++pi)
                #pragma unroll
                for (int nt = 0; nt < 4; ++nt)
                    bb[pi][nt] = *(const bf16x8*)(wb + (size_t)(pi * 4 + nt) * 512);

            #pragma unroll
            for (int ci = 0; ci < 16; ++ci) {              // k = 32*ci
                const int p = ci % 3;
                const bf16* Asrc = (ci < 8) ? Alo : Ahi;   // static under unroll
                const int segb = (ci & 7) * 4 + quad;
                bf16x8 a[2];
                #pragma unroll
                for (int mt = 0; mt < 2; ++mt) {
                    int row  = mt * 16 + l15;
                    int pseg = (segb & 24) | ((segb & 7) ^ (row & 7));
                    a[mt] = *(const bf16x8*)&Asrc[row * 256 + pseg * 8];
                }
                #pragma unroll
                for (int mt = 0; mt < 2; ++mt)
                    #pragma unroll
                    for (int nt = 0; nt < 4; ++nt)
                        acc[mt][nt] = __builtin_amdgcn_mfma_f32_16x16x32_bf16(
                            a[mt], bb[p][nt], acc[mt][nt], 0, 0, 0);
                if (ci + 3 < 16) {
                    #pragma unroll
                    for (int nt = 0; nt < 4; ++nt)
                        bb[p][nt] = *(const bf16x8*)(wb + (size_t)((ci + 3) * 4 + nt) * 512);
                }
            }

            __syncthreads();   // all MFMA reads of sH[L] done before overwrite

            // Epilogue. C/D: col = l15 (+16nt +64wv), row = quad*4+reg.
            // Lane pair (l, l^1) shares d; even lane does regs 0,1, odd 2,3.
            {
                const int odd = lane & 1;
                #pragma unroll
                for (int nt = 0; nt < 4; ++nt) {
                    const int d = (w64 + nt * 16 + l15) >> 1;
                    const float2 bb2 = bias[L][nt];
                    #pragma unroll
                    for (int mt = 0; mt < 2; ++mt) {
                        f32x4 v = acc[mt][nt];
                        float pp[4];
                        #pragma unroll
                        for (int r = 0; r < 4; ++r) pp[r] = __shfl_xor(v[r], 1);
                        #pragma unroll
                        for (int rr = 0; rr < 2; ++rr) {
                            const int r = (odd ? 2 : 0) + rr;
                            float tpre = (odd ? pp[r] : v[r]) + bb2.x;
                            float fpre = (odd ? v[r] : pp[r]) + bb2.y;
                            tpre = fminf(30.f, fmaxf(-30.f, tpre));
                            fpre = fminf(15.f, fmaxf(-15.f, fpre));
                            // h/(sigma(t)+1e-6) == h*(1+u)/(1+eps+eps*u), u=e^-t
                            float u   = __expf(-tpre);
                            float den = 1.0f + 1e-6f + 1e-6f * u;
                            float rcp = __builtin_amdgcn_rcpf(den);
                            float e2  = __expf(2.0f * fpre);
                            float r2  = __builtin_amdgcn_rcpf(e2 + 1.0f);
                            float fo  = (e2 - 1.0f) * r2;
                            const int row = mt * 16 + quad * 4 + r;
                            const int seg = d >> 3;
                            const int idx = row * 256 +
                                (((seg & 24) | ((seg & 7) ^ (row & 7))) << 3) + (d & 7);
                            float h  = (float)Ahi[idx];
                            float g  = h * (1.0f + u) * rcp;
                            float nv = h + DT * (fo - g);
                            nv = fminf(10.0f, fmaxf(-10.0f, nv));
                            Ahi[idx] = (bf16)nv;
                            dmax = fmaxf(dmax, fabsf(nv - h));
                        }
                    }
                }
            }
            if (L == NLAYER - 1) {
                #pragma unroll
                for (int off = 32; off > 0; off >>= 1)
                    dmax = fmaxf(dmax, __shfl_xor(dmax, off));
                if (lane == 0) sRed[wv] = dmax;
            }
            __syncthreads();   // h updates (and sRed) visible
        } // L

        if (tid == 0) {
            float m = sRed[0];
            #pragma unroll
            for (int w = 1; w < 8; ++w) m = fmaxf(m, sRed[w]);
            atomicMax((unsigned int*)(deltas + t), __float_as_uint(m));
        }
    } // t

    // ---- final output: layer-3 states, de-swizzled, bf16 -> fp32 ----
    #pragma unroll
    for (int it = 0; it < 2; ++it) {
        int s = tid + it * 512;
        int r = s >> 5, seg = s & 31;
        int pseg = (seg & 24) | ((seg & 7) ^ (r & 7));
        bf16x8 v = *(const bf16x8*)&sH[NLAYER - 1][r * 256 + pseg * 8];
        float* go = out + (rowbase + r) * HID + seg * 8;
        float4 o0 = {(float)v[0], (float)v[1], (float)v[2], (float)v[3]};
        float4 o1 = {(float)v[4], (float)v[5], (float)v[6], (float)v[7]};
        *(float4*)go = o0;
        *(float4*)(go + 4) = o1;
    }
}

__global__ void result_kernel(const float* __restrict__ deltas,
                              float* __restrict__ out) {
    if (threadIdx.x == 0) {
        int res = TMAX;
        for (int t = 0; t < TMAX; ++t) {
            if (deltas[t] < EPSC) { res = t; break; }
        }
        out[(size_t)ROWS * HID] = (float)res;
    }
}

// ---------------------------------------------------------------------------
extern "C" void kernel_launch(void* const* d_in, const int* in_sizes, int n_in,
                              void* d_out, int out_size, void* d_ws, size_t ws_size,
                              hipStream_t stream) {
    const float* x  = (const float*)d_in[0];
    const float* Ws = (const float*)d_in[1];
    const float* bs = (const float*)d_in[2];
    const float* Wi = (const float*)d_in[3];
    const float* bi = (const float*)d_in[4];
    const float* Wt = (const float*)d_in[5];
    const float* bt = (const float*)d_in[6];
    float* out = (float*)d_out;

    char* p = (char*)d_ws;
    bf16*  Wf     = (bf16*)p;  p += (size_t)NLAYER * TWOH * TWOH * sizeof(bf16); // 2 MB
    float* bp     = (float*)p; p += (size_t)NLAYER * TWOH * sizeof(float);       // 8 KB
    float* deltas = (float*)p; p += 64 * sizeof(float);

    hipMemsetAsync(deltas, 0, 64 * sizeof(float), stream);
    pack_w_kernel<<<(NLAYER * TWOH * TWOH) / 256, 256, 0, stream>>>(Ws, Wi, Wt, Wf);
    pack_b_kernel<<<(NLAYER * TWOH) / 256, 256, 0, stream>>>(bs, bi, bt, bp);

    persistent_kernel<<<256, 512, 0, stream>>>(x, Wf, bp, deltas, out);
    result_kernel<<<1, 64, 0, stream>>>(deltas, out);
}

// Round 6
// 1344.027 us; speedup vs baseline: 3.9601x; 3.9601x over previous
//
#include <hip/hip_runtime.h>
#include <math.h>

#define HID 256
#define TWOH 512
#define ROWS 8192   // B*S
#define NLAYER 4
#define TMAX 50
#define DT 0.05f
#define EPSC 1e-3f

typedef __bf16 bf16;
typedef __bf16 bf16x8 __attribute__((ext_vector_type(8)));
typedef float f32x4 __attribute__((ext_vector_type(4)));

// ---------------------------------------------------------------------------
// Fragment-major weight packing. Logical B[n][k] per layer with interleaved
// columns: n=2d -> tau col d (Wt[d][k]); n=2d+1 -> forcing col d
// (k<256 ? Wi[d][k] : Ws[d][k-256]).
// Wave wv, k-chunk ci, n-tile nt reads ONE contiguous 1-KB fragment:
// e = (((L*8+wv)*16+ci)*4+nt)*512 + lane*8 + j,
// n = wv*64 + nt*16 + (lane&15), k = ci*32 + (lane>>4)*8 + j.
// ---------------------------------------------------------------------------
__global__ void pack_w_kernel(const float* __restrict__ Ws,
                              const float* __restrict__ Wi,
                              const float* __restrict__ Wt,
                              bf16* __restrict__ Wf) {
    int e = blockIdx.x * 256 + threadIdx.x;     // [0, 4*512*512)
    int j    = e & 7;
    int lane = (e >> 3) & 63;
    int nt   = (e >> 9) & 3;
    int ci   = (e >> 11) & 15;
    int wv   = (e >> 15) & 7;
    int L    = (e >> 18);
    int n = wv * 64 + nt * 16 + (lane & 15);
    int k = ci * 32 + (lane >> 4) * 8 + j;
    int d = n >> 1;
    float v;
    if ((n & 1) == 0) {
        v = Wt[(size_t)L * HID * TWOH + (size_t)d * TWOH + k];
    } else {
        v = (k < HID) ? Wi[(size_t)L * HID * HID + (size_t)d * HID + k]
                      : Ws[(size_t)L * HID * HID + (size_t)d * HID + (k - HID)];
    }
    Wf[e] = (bf16)v;
}

__global__ void pack_b_kernel(const float* __restrict__ bs,
                              const float* __restrict__ bi,
                              const float* __restrict__ bt,
                              float* __restrict__ bp) {
    int idx = blockIdx.x * 256 + threadIdx.x;   // [0, 4*512)
    int L = idx / TWOH;
    int n = idx % TWOH;
    int d = n >> 1;
    bp[idx] = ((n & 1) == 0) ? bt[L * HID + d]
                             : (bs[L * HID + d] + bi[L * HID + d]);
}

// ---------------------------------------------------------------------------
// Persistent kernel: block b owns rows [32b, 32b+32) for all 50 t x 4 layers.
// States LDS-resident bf16 (XOR-swizzled). Weights stream L2 -> registers as
// contiguous 1-KB fragments, depth-3 prefetch. 8 waves split n (64 each).
// L-loop kept ROLLED (round-5 full unroll bloated code + spilled). Biases in
// an LDS table (dynamic L index costs no VGPRs) -> demand < 128-VGPR cap.
// ---------------------------------------------------------------------------
__global__ __launch_bounds__(512, 1) void persistent_kernel(
    const float* __restrict__ x,
    const bf16* __restrict__ Wf,
    const float* __restrict__ bp,
    float* __restrict__ deltas,
    float* __restrict__ out)
{
    __shared__ bf16 sX[32 * 256];            // 16 KB
    __shared__ bf16 sH[NLAYER][32 * 256];    // 64 KB
    __shared__ float2 sBias[NLAYER][256];    //  8 KB  (b_tau, b_forcing) per d
    __shared__ float sRed[8];

    const int tid  = threadIdx.x;
    const int lane = tid & 63;
    const int wv   = tid >> 6;               // 0..7
    const int l15  = lane & 15;
    const int quad = lane >> 4;              // 0..3
    const int w64  = wv * 64;
    const size_t rowbase = (size_t)blockIdx.x * 32;

    // ---- stage x -> sX (bf16, swizzled); zero sH; load bias table ----
    #pragma unroll
    for (int it = 0; it < 2; ++it) {
        int s = tid + it * 512;              // 32 rows x 32 segs
        int r = s >> 5, seg = s & 31;
        const float* gx = x + (rowbase + r) * HID + seg * 8;
        float4 v0 = *(const float4*)gx;
        float4 v1 = *(const float4*)(gx + 4);
        bf16x8 o;
        o[0]=(bf16)v0.x; o[1]=(bf16)v0.y; o[2]=(bf16)v0.z; o[3]=(bf16)v0.w;
        o[4]=(bf16)v1.x; o[5]=(bf16)v1.y; o[6]=(bf16)v1.z; o[7]=(bf16)v1.w;
        int pseg = (seg & 24) | ((seg & 7) ^ (r & 7));
        *(bf16x8*)&sX[r * 256 + pseg * 8] = o;
    }
    {
        bf16x8 z = {};
        bf16* hflat = &sH[0][0];
        #pragma unroll
        for (int it = 0; it < 8; ++it)
            *(bf16x8*)&hflat[(size_t)(tid + it * 512) * 8] = z;
    }
    #pragma unroll
    for (int it = 0; it < 2; ++it) {
        int i = tid + it * 512;              // [0, 1024): L = i>>8, d = i&255
        sBias[i >> 8][i & 255] = *(const float2*)(bp + (i >> 8) * TWOH + 2 * (i & 255));
    }

    __syncthreads();

    for (int t = 0; t < TMAX; ++t) {
        float dmax = 0.0f;
        for (int L = 0; L < NLAYER; ++L) {
            const bf16* Alo = (L == 0) ? sX : sH[L - 1];   // k < 256 (cur_in)
            bf16*       Ahi = sH[L];                       // k >= 256 (h_prev)
            // wave's fragment stream: 64 KB contiguous per (L, wv)
            const bf16* wb = Wf + ((size_t)(L * 8 + wv) * 32768) + (size_t)lane * 8;

            f32x4 acc[2][4];
            #pragma unroll
            for (int mt = 0; mt < 2; ++mt)
                #pragma unroll
                for (int nt = 0; nt < 4; ++nt)
                    acc[mt][nt] = (f32x4){0.f, 0.f, 0.f, 0.f};

            // depth-3 register prefetch of B fragments (1 KB each, contiguous)
            bf16x8 bb[3][4];
            #pragma unroll
            for (int pi = 0; pi < 3; ++pi)
                #pragma unroll
                for (int nt = 0; nt < 4; ++nt)
                    bb[pi][nt] = *(const bf16x8*)(wb + (size_t)(pi * 4 + nt) * 512);

            #pragma unroll
            for (int ci = 0; ci < 16; ++ci) {              // k = 32*ci
                const int p = ci % 3;
                const bf16* Asrc = (ci < 8) ? Alo : Ahi;   // static under unroll
                const int segb = (ci & 7) * 4 + quad;
                bf16x8 a[2];
                #pragma unroll
                for (int mt = 0; mt < 2; ++mt) {
                    int row  = mt * 16 + l15;
                    int pseg = (segb & 24) | ((segb & 7) ^ (row & 7));
                    a[mt] = *(const bf16x8*)&Asrc[row * 256 + pseg * 8];
                }
                #pragma unroll
                for (int mt = 0; mt < 2; ++mt)
                    #pragma unroll
                    for (int nt = 0; nt < 4; ++nt)
                        acc[mt][nt] = __builtin_amdgcn_mfma_f32_16x16x32_bf16(
                            a[mt], bb[p][nt], acc[mt][nt], 0, 0, 0);
                if (ci + 3 < 16) {
                    #pragma unroll
                    for (int nt = 0; nt < 4; ++nt)
                        bb[p][nt] = *(const bf16x8*)(wb + (size_t)((ci + 3) * 4 + nt) * 512);
                }
            }

            __syncthreads();   // all MFMA reads of sH[L] done before overwrite

            // Epilogue. C/D: col = l15 (+16nt +64wv), row = quad*4+reg.
            // Lane pair (l, l^1) shares d; even lane does regs 0,1, odd 2,3.
            {
                const int odd = lane & 1;
                #pragma unroll
                for (int nt = 0; nt < 4; ++nt) {
                    const int d = (w64 + nt * 16 + l15) >> 1;
                    const float2 bb2 = sBias[L][d];
                    #pragma unroll
                    for (int mt = 0; mt < 2; ++mt) {
                        f32x4 v = acc[mt][nt];
                        float pp[4];
                        #pragma unroll
                        for (int r = 0; r < 4; ++r) pp[r] = __shfl_xor(v[r], 1);
                        #pragma unroll
                        for (int rr = 0; rr < 2; ++rr) {
                            const int r = (odd ? 2 : 0) + rr;
                            float tpre = (odd ? pp[r] : v[r]) + bb2.x;
                            float fpre = (odd ? v[r] : pp[r]) + bb2.y;
                            tpre = fminf(30.f, fmaxf(-30.f, tpre));
                            fpre = fminf(15.f, fmaxf(-15.f, fpre));
                            // h/(sigma(t)+1e-6) == h*(1+u)/(1+eps+eps*u), u=e^-t
                            float u   = __expf(-tpre);
                            float den = 1.0f + 1e-6f + 1e-6f * u;
                            float rcp = __builtin_amdgcn_rcpf(den);
                            float e2  = __expf(2.0f * fpre);
                            float r2  = __builtin_amdgcn_rcpf(e2 + 1.0f);
                            float fo  = (e2 - 1.0f) * r2;
                            const int row = mt * 16 + quad * 4 + r;
                            const int seg = d >> 3;
                            const int idx = row * 256 +
                                (((seg & 24) | ((seg & 7) ^ (row & 7))) << 3) + (d & 7);
                            float h  = (float)Ahi[idx];
                            float g  = h * (1.0f + u) * rcp;
                            float nv = h + DT * (fo - g);
                            nv = fminf(10.0f, fmaxf(-10.0f, nv));
                            Ahi[idx] = (bf16)nv;
                            dmax = fmaxf(dmax, fabsf(nv - h));
                        }
                    }
                }
            }
            if (L == NLAYER - 1) {
                #pragma unroll
                for (int off = 32; off > 0; off >>= 1)
                    dmax = fmaxf(dmax, __shfl_xor(dmax, off));
                if (lane == 0) sRed[wv] = dmax;
            }
            __syncthreads();   // h updates (and sRed) visible
        } // L

        if (tid == 0) {
            float m = sRed[0];
            #pragma unroll
            for (int w = 1; w < 8; ++w) m = fmaxf(m, sRed[w]);
            atomicMax((unsigned int*)(deltas + t), __float_as_uint(m));
        }
    } // t

    // ---- final output: layer-3 states, de-swizzled, bf16 -> fp32 ----
    #pragma unroll
    for (int it = 0; it < 2; ++it) {
        int s = tid + it * 512;
        int r = s >> 5, seg = s & 31;
        int pseg = (seg & 24) | ((seg & 7) ^ (r & 7));
        bf16x8 v = *(const bf16x8*)&sH[NLAYER - 1][r * 256 + pseg * 8];
        float* go = out + (rowbase + r) * HID + seg * 8;
        float4 o0 = {(float)v[0], (float)v[1], (float)v[2], (float)v[3]};
        float4 o1 = {(float)v[4], (float)v[5], (float)v[6], (float)v[7]};
        *(float4*)go = o0;
        *(float4*)(go + 4) = o1;
    }
}

__global__ void result_kernel(const float* __restrict__ deltas,
                              float* __restrict__ out) {
    if (threadIdx.x == 0) {
        int res = TMAX;
        for (int t = 0; t < TMAX; ++t) {
            if (deltas[t] < EPSC) { res = t; break; }
        }
        out[(size_t)ROWS * HID] = (float)res;
    }
}

// ---------------------------------------------------------------------------
extern "C" void kernel_launch(void* const* d_in, const int* in_sizes, int n_in,
                              void* d_out, int out_size, void* d_ws, size_t ws_size,
                              hipStream_t stream) {
    const float* x  = (const float*)d_in[0];
    const float* Ws = (const float*)d_in[1];
    const float* bs = (const float*)d_in[2];
    const float* Wi = (const float*)d_in[3];
    const float* bi = (const float*)d_in[4];
    const float* Wt = (const float*)d_in[5];
    const float* bt = (const float*)d_in[6];
    float* out = (float*)d_out;

    char* p = (char*)d_ws;
    bf16*  Wf     = (bf16*)p;  p += (size_t)NLAYER * TWOH * TWOH * sizeof(bf16); // 2 MB
    float* bp     = (float*)p; p += (size_t)NLAYER * TWOH * sizeof(float);       // 8 KB
    float* deltas = (float*)p; p += 64 * sizeof(float);

    hipMemsetAsync(deltas, 0, 64 * sizeof(float), stream);
    pack_w_kernel<<<(NLAYER * TWOH * TWOH) / 256, 256, 0, stream>>>(Ws, Wi, Wt, Wf);
    pack_b_kernel<<<(NLAYER * TWOH) / 256, 256, 0, stream>>>(bs, bi, bt, bp);

    persistent_kernel<<<256, 512, 0, stream>>>(x, Wf, bp, deltas, out);
    result_kernel<<<1, 64, 0, stream>>>(deltas, out);
}

// Round 7
// 1227.223 us; speedup vs baseline: 4.3370x; 1.0952x over previous
//
#include <hip/hip_runtime.h>
#include <math.h>

#define HID 256
#define TWOH 512
#define ROWS 8192   // B*S
#define NLAYER 4
#define TMAX 50
#define DT 0.05f
#define EPSC 1e-3f

typedef float f32x4 __attribute__((ext_vector_type(4)));
typedef unsigned char u8;

// fp8 helpers (OCP e4m3 on gfx950)
__device__ inline u8 f32_to_fp8(float v) {
    return (u8)(__builtin_amdgcn_cvt_pk_fp8_f32(v, v, 0, 0) & 0xff);
}
__device__ inline float fp8_to_f32(u8 b) {
    return __builtin_amdgcn_cvt_f32_fp8((int)b, 0);
}

// ---------------------------------------------------------------------------
// Fragment-major fp8 weight packing. Per wave wv (d-range [wv*32,wv*32+32)):
//   nt 0,1 -> tau columns   (d = wv*32 + nt*16 + l15)
//   nt 2,3 -> forcing cols  (d = wv*32 + (nt-2)*16 + l15)
// Fragment (L,wv,ci,nt) is 512 B contiguous: lane*8 + j, k = ci*32+quad*8+j.
// e bits: j:0-2, lane:3-8, nt:9-10, ci:11-14, wv:15-17, L:18-19.
// tau row d: Wt[d][k]; forcing row d: k<256 ? Wi[d][k] : Ws[d][k-256].
// ---------------------------------------------------------------------------
__global__ void pack_w_kernel(const float* __restrict__ Ws,
                              const float* __restrict__ Wi,
                              const float* __restrict__ Wt,
                              u8* __restrict__ Wf) {
    int e = blockIdx.x * 256 + threadIdx.x;     // [0, 2^20)
    int j    = e & 7;
    int lane = (e >> 3) & 63;
    int nt   = (e >> 9) & 3;
    int ci   = (e >> 11) & 15;
    int wv   = (e >> 15) & 7;
    int L    = (e >> 18);
    int l15  = lane & 15;
    int quad = lane >> 4;
    int d = wv * 32 + (nt & 1) * 16 + l15;
    int k = ci * 32 + quad * 8 + j;
    float v;
    if ((nt >> 1) == 0) {
        v = Wt[(size_t)L * HID * TWOH + (size_t)d * TWOH + k];
    } else {
        v = (k < HID) ? Wi[(size_t)L * HID * HID + (size_t)d * HID + k]
                      : Ws[(size_t)L * HID * HID + (size_t)d * HID + (k - HID)];
    }
    Wf[e] = f32_to_fp8(v);
}

__global__ void pack_b_kernel(const float* __restrict__ bs,
                              const float* __restrict__ bi,
                              const float* __restrict__ bt,
                              float* __restrict__ bp) {
    int idx = blockIdx.x * 256 + threadIdx.x;   // [0, 4*512): L*512 + n, n=2d/2d+1
    int L = idx / TWOH;
    int n = idx % TWOH;
    int d = n >> 1;
    bp[idx] = ((n & 1) == 0) ? bt[L * HID + d]
                             : (bs[L * HID + d] + bi[L * HID + d]);
}

// ---------------------------------------------------------------------------
// Persistent kernel: block b owns rows [32b,32b+32) for all 50 t x 4 layers.
// States LDS-resident fp8 (256 B/row, 8-B segs, pseg = seg ^ row swizzle ->
// conflict-free ds_read_b64 A-frags). Weights stream L2 -> registers as 512-B
// fp8 fragments, depth-4 prefetch. 8 waves split n; no epilogue shuffles
// (tau/forcing of the same d live in the same lane, nt and nt+2).
// ---------------------------------------------------------------------------
__global__ __launch_bounds__(512, 1) void persistent_kernel(
    const float* __restrict__ x,
    const u8* __restrict__ Wf,
    const float* __restrict__ bp,
    float* __restrict__ deltas,
    float* __restrict__ out)
{
    __shared__ u8 sX[32 * 256];              //  8 KB
    __shared__ u8 sH[NLAYER][32 * 256];      // 32 KB
    __shared__ float2 sBias[NLAYER][256];    //  8 KB (b_tau, b_forcing) per d
    __shared__ float sRed[8];

    const int tid  = threadIdx.x;
    const int lane = tid & 63;
    const int wv   = tid >> 6;               // 0..7
    const int l15  = lane & 15;
    const int quad = lane >> 4;              // 0..3
    const int w32  = wv * 32;                // wave's d-base
    const size_t rowbase = (size_t)blockIdx.x * 32;

    // ---- stage x -> sX (fp8, swizzled); zero sH; load bias table ----
    #pragma unroll
    for (int it = 0; it < 2; ++it) {
        int s = tid + it * 512;              // 32 rows x 32 segs
        int r = s >> 5, seg = s & 31;
        const float* gx = x + (rowbase + r) * HID + seg * 8;
        float4 v0 = *(const float4*)gx;
        float4 v1 = *(const float4*)(gx + 4);
        int lo = __builtin_amdgcn_cvt_pk_fp8_f32(v0.x, v0.y, 0, 0);
        lo     = __builtin_amdgcn_cvt_pk_fp8_f32(v0.z, v0.w, lo, 1);
        int hi = __builtin_amdgcn_cvt_pk_fp8_f32(v1.x, v1.y, 0, 0);
        hi     = __builtin_amdgcn_cvt_pk_fp8_f32(v1.z, v1.w, hi, 1);
        long pk = ((long)(unsigned int)lo) | ((long)hi << 32);
        *(long*)&sX[r * 256 + (seg ^ r) * 8] = pk;
    }
    {
        long* hflat = (long*)&sH[0][0];
        #pragma unroll
        for (int it = 0; it < 8; ++it) hflat[tid + it * 512] = 0;
    }
    #pragma unroll
    for (int it = 0; it < 2; ++it) {
        int i = tid + it * 512;              // [0,1024): L = i>>8, d = i&255
        sBias[i >> 8][i & 255] = *(const float2*)(bp + (i >> 8) * TWOH + 2 * (i & 255));
    }

    __syncthreads();

    for (int t = 0; t < TMAX; ++t) {
        float dmax = 0.0f;
        for (int L = 0; L < NLAYER; ++L) {
            const u8* Alo = (L == 0) ? sX : sH[L - 1];   // k < 256 (cur_in)
            u8*       Ahi = sH[L];                       // k >= 256 (h_prev)
            // wave's fragment stream: 32 KB contiguous per (L, wv)
            const u8* wb = Wf + ((size_t)(L * 8 + wv) * 32768) + (size_t)lane * 8;

            f32x4 acc[2][4];
            #pragma unroll
            for (int mt = 0; mt < 2; ++mt)
                #pragma unroll
                for (int nt = 0; nt < 4; ++nt)
                    acc[mt][nt] = (f32x4){0.f, 0.f, 0.f, 0.f};

            // depth-4 register prefetch of B fragments (512 B each, contiguous)
            long bb[4][4];
            #pragma unroll
            for (int pi = 0; pi < 4; ++pi)
                #pragma unroll
                for (int nt = 0; nt < 4; ++nt)
                    bb[pi][nt] = *(const long*)(wb + (size_t)(pi * 4 + nt) * 512);

            #pragma unroll
            for (int ci = 0; ci < 16; ++ci) {            // k = 32*ci
                const int p = ci & 3;
                const u8* Asrc = (ci < 8) ? Alo : Ahi;   // static under unroll
                const int seg = (ci & 7) * 4 + quad;     // 8-B seg in [0,32)
                long a[2];
                #pragma unroll
                for (int mt = 0; mt < 2; ++mt) {
                    int row = mt * 16 + l15;
                    a[mt] = *(const long*)&Asrc[row * 256 + (seg ^ row) * 8];
                }
                #pragma unroll
                for (int mt = 0; mt < 2; ++mt)
                    #pragma unroll
                    for (int nt = 0; nt < 4; ++nt)
                        acc[mt][nt] = __builtin_amdgcn_mfma_f32_16x16x32_fp8_fp8(
                            a[mt], bb[p][nt], acc[mt][nt], 0, 0, 0);
                if (ci + 4 < 16) {
                    #pragma unroll
                    for (int nt = 0; nt < 4; ++nt)
                        bb[p][nt] = *(const long*)(wb + (size_t)((ci + 4) * 4 + nt) * 512);
                }
            }

            __syncthreads();   // all MFMA reads of sH[L] done before overwrite

            // Epilogue. C/D: col = l15 (tile nt), row = quad*4+reg.
            // tau-pre in acc[mt][ntp], forcing-pre in acc[mt][ntp+2], same lane.
            #pragma unroll
            for (int ntp = 0; ntp < 2; ++ntp) {
                const int d = w32 + ntp * 16 + l15;
                const float2 bb2 = sBias[L][d];
                const int seg = d >> 3, dlow = d & 7;
                #pragma unroll
                for (int mt = 0; mt < 2; ++mt) {
                    #pragma unroll
                    for (int r = 0; r < 4; ++r) {
                        float tpre = acc[mt][ntp][r]     + bb2.x;
                        float fpre = acc[mt][ntp + 2][r] + bb2.y;
                        tpre = fminf(30.f, fmaxf(-30.f, tpre));
                        fpre = fminf(15.f, fmaxf(-15.f, fpre));
                        // h/(sigma(t)+1e-6) == h*(1+u)/(1+eps+eps*u), u=e^-t
                        float u   = __expf(-tpre);
                        float den = 1.0f + 1e-6f + 1e-6f * u;
                        float rcp = __builtin_amdgcn_rcpf(den);
                        float e2  = __expf(2.0f * fpre);
                        float r2  = __builtin_amdgcn_rcpf(e2 + 1.0f);
                        float fo  = (e2 - 1.0f) * r2;
                        const int row = mt * 16 + quad * 4 + r;
                        const int idx = row * 256 + (seg ^ row) * 8 + dlow;
                        float h  = fp8_to_f32(Ahi[idx]);
                        float g  = h * (1.0f + u) * rcp;
                        float nv = h + DT * (fo - g);
                        nv = fminf(10.0f, fmaxf(-10.0f, nv));
                        Ahi[idx] = f32_to_fp8(nv);
                        dmax = fmaxf(dmax, fabsf(nv - h));
                    }
                }
            }
            if (L == NLAYER - 1) {
                #pragma unroll
                for (int off = 32; off > 0; off >>= 1)
                    dmax = fmaxf(dmax, __shfl_xor(dmax, off));
                if (lane == 0) sRed[wv] = dmax;
            }
            __syncthreads();   // h updates (and sRed) visible
        } // L

        if (tid == 0) {
            float m = sRed[0];
            #pragma unroll
            for (int w = 1; w < 8; ++w) m = fmaxf(m, sRed[w]);
            atomicMax((unsigned int*)(deltas + t), __float_as_uint(m));
        }
    } // t

    // ---- final output: layer-3 states, de-swizzled, fp8 -> fp32 ----
    #pragma unroll
    for (int it = 0; it < 2; ++it) {
        int s = tid + it * 512;
        int r = s >> 5, seg = s & 31;
        long v = *(const long*)&sH[NLAYER - 1][r * 256 + (seg ^ r) * 8];
        int lo = (int)(v & 0xffffffffl);
        int hi = (int)(v >> 32);
        float* go = out + (rowbase + r) * HID + seg * 8;
        float4 o0, o1;
        o0.x = __builtin_amdgcn_cvt_f32_fp8(lo, 0);
        o0.y = __builtin_amdgcn_cvt_f32_fp8(lo, 1);
        o0.z = __builtin_amdgcn_cvt_f32_fp8(lo, 2);
        o0.w = __builtin_amdgcn_cvt_f32_fp8(lo, 3);
        o1.x = __builtin_amdgcn_cvt_f32_fp8(hi, 0);
        o1.y = __builtin_amdgcn_cvt_f32_fp8(hi, 1);
        o1.z = __builtin_amdgcn_cvt_f32_fp8(hi, 2);
        o1.w = __builtin_amdgcn_cvt_f32_fp8(hi, 3);
        *(float4*)go = o0;
        *(float4*)(go + 4) = o1;
    }
}

__global__ void result_kernel(const float* __restrict__ deltas,
                              float* __restrict__ out) {
    if (threadIdx.x == 0) {
        int res = TMAX;
        for (int t = 0; t < TMAX; ++t) {
            if (deltas[t] < EPSC) { res = t; break; }
        }
        out[(size_t)ROWS * HID] = (float)res;
    }
}

// ---------------------------------------------------------------------------
extern "C" void kernel_launch(void* const* d_in, const int* in_sizes, int n_in,
                              void* d_out, int out_size, void* d_ws, size_t ws_size,
                              hipStream_t stream) {
    const float* x  = (const float*)d_in[0];
    const float* Ws = (const float*)d_in[1];
    const float* bs = (const float*)d_in[2];
    const float* Wi = (const float*)d_in[3];
    const float* bi = (const float*)d_in[4];
    const float* Wt = (const float*)d_in[5];
    const float* bt = (const float*)d_in[6];
    float* out = (float*)d_out;

    char* p = (char*)d_ws;
    u8*    Wf     = (u8*)p;    p += (size_t)NLAYER * TWOH * TWOH;            // 1 MB
    float* bp     = (float*)p; p += (size_t)NLAYER * TWOH * sizeof(float);   // 8 KB
    float* deltas = (float*)p; p += 64 * sizeof(float);

    hipMemsetAsync(deltas, 0, 64 * sizeof(float), stream);
    pack_w_kernel<<<(NLAYER * TWOH * TWOH) / 256, 256, 0, stream>>>(Ws, Wi, Wt, Wf);
    pack_b_kernel<<<(NLAYER * TWOH) / 256, 256, 0, stream>>>(bs, bi, bt, bp);

    persistent_kernel<<<256, 512, 0, stream>>>(x, Wf, bp, deltas, out);
    result_kernel<<<1, 64, 0, stream>>>(deltas, out);
}